// Round 3
// baseline (651.381 us; speedup 1.0000x reference)
//
#include <hip/hip_runtime.h>
#include <math.h>

// MultiHeadSelfAttention: B=4, S=2048, E=1024, H=16, Dh=64. fp32 in/out,
// bf16 MFMA internally, fp32 accumulate.
//
// Stage 1: qkv_gemm -> ws (bf16): q (pre-scaled by log2e/32) [bh][s][d],
//                                 k [bh][s][d], v TRANSPOSED [bh][d][s]
// Stage 2: attn     -> barrier-free flash attention (S^T = K Q^T trick),
//                      bf16 out [b*s][h*64+d] in ws
// Stage 3: out_gemm -> @ Wo^T + bo -> d_out (fp32)

typedef __bf16 bf16;
typedef __attribute__((ext_vector_type(8))) short short8;
typedef __attribute__((ext_vector_type(4))) short s4v;
typedef __attribute__((ext_vector_type(4))) float floatx4;

#define MFMA16(a, b, c) __builtin_amdgcn_mfma_f32_16x16x32_bf16((a), (b), (c), 0, 0, 0)

#define LDS_STRIDE 56   // GEMM tiles: 32 -> 56 shorts (112 B)
#define PQ_STRIDE 144   // P rows: 128 -> 144 shorts (288 B, 16B-aligned)

// Q pre-scale: (1/sqrt(1024)) * log2(e) -> softmax computed in base-2 domain
#define QSCALE 0.04508422002778f

// 8 contiguous elements -> 8 bf16 (short8 bit pattern)
__device__ __forceinline__ short8 frag8(const bf16* __restrict__ p) {
    return *(const short8*)p;
}
__device__ __forceinline__ short8 frag8(const float* __restrict__ p) {
    const floatx4 a = *(const floatx4*)p;
    const floatx4 b = *(const floatx4*)(p + 4);
    short8 r;
#pragma unroll
    for (int j = 0; j < 4; j++) {
        r[j]     = __builtin_bit_cast(short, (bf16)a[j]);
        r[4 + j] = __builtin_bit_cast(short, (bf16)b[j]);
    }
    return r;
}

// ---------------------------------------------------------------------------
// 128x128-tile GEMM core: C[m][n] = sum_k A[m][k] * B[n][k]
// ---------------------------------------------------------------------------
template <typename TA, typename TB>
__device__ __forceinline__ void gemm128_core(
    const TA* __restrict__ A, const TB* __restrict__ B, int K,
    int m0, int n0, short* As, short* Bs, floatx4 acc[4][4])
{
    const int tid  = threadIdx.x;
    const int lane = tid & 63;
    const int w    = tid >> 6;
    const int wm   = w >> 1, wn = w & 1;
    const int g    = lane >> 4, c = lane & 15;
    const int lrow = tid >> 2;
    const int lc8  = (tid & 3) * 8;

#pragma unroll
    for (int mi = 0; mi < 4; mi++)
#pragma unroll
        for (int ni = 0; ni < 4; ni++)
            acc[mi][ni] = (floatx4){0.f, 0.f, 0.f, 0.f};

    for (int k0 = 0; k0 < K; k0 += 32) {
        *(short8*)(As + lrow * LDS_STRIDE + lc8) =
            frag8(A + (size_t)(m0 + lrow) * K + k0 + lc8);
        *(short8*)(As + (lrow + 64) * LDS_STRIDE + lc8) =
            frag8(A + (size_t)(m0 + lrow + 64) * K + k0 + lc8);
        *(short8*)(Bs + lrow * LDS_STRIDE + lc8) =
            frag8(B + (size_t)(n0 + lrow) * K + k0 + lc8);
        *(short8*)(Bs + (lrow + 64) * LDS_STRIDE + lc8) =
            frag8(B + (size_t)(n0 + lrow + 64) * K + k0 + lc8);
        __syncthreads();

        short8 af[4], bfr[4];
#pragma unroll
        for (int mi = 0; mi < 4; mi++)
            af[mi] = *(const short8*)(As + (wm * 64 + mi * 16 + c) * LDS_STRIDE + g * 8);
#pragma unroll
        for (int ni = 0; ni < 4; ni++)
            bfr[ni] = *(const short8*)(Bs + (wn * 64 + ni * 16 + c) * LDS_STRIDE + g * 8);
#pragma unroll
        for (int mi = 0; mi < 4; mi++)
#pragma unroll
            for (int ni = 0; ni < 4; ni++)
                acc[mi][ni] = MFMA16(af[mi], bfr[ni], acc[mi][ni]);
        __syncthreads();
    }
}

// ---------------------------------------------------------------------------
// Stage 1: q/k/v projections. q scaled by QSCALE, [bh][s][64].
//          k plain [bh][s][64]. v stored TRANSPOSED [bh][64][2048].
// grid (8, 64, 3), block 256
// ---------------------------------------------------------------------------
__global__ __launch_bounds__(256) void qkv_gemm(
    const float* __restrict__ X,
    const float* __restrict__ Wq, const float* __restrict__ Wk, const float* __restrict__ Wv,
    const float* __restrict__ bq, const float* __restrict__ bk, const float* __restrict__ bv,
    bf16* __restrict__ qkv)
{
    __shared__ __align__(16) short As[128 * LDS_STRIDE];
    __shared__ __align__(16) short Bs[128 * LDS_STRIDE];

    const int z = blockIdx.z;
    const float* W    = (z == 0) ? Wq : (z == 1) ? Wk : Wv;
    const float* bias = (z == 0) ? bq : (z == 1) ? bk : bv;
    bf16* outz = qkv + (size_t)z * (8192u * 1024u);
    const float oscale = (z == 0) ? QSCALE : 1.0f;

    const int m0 = blockIdx.y * 128;
    const int n0 = blockIdx.x * 128;

    floatx4 acc[4][4];
    gemm128_core(X, W, 1024, m0, n0, As, Bs, acc);

    const int lane = threadIdx.x & 63;
    const int w = threadIdx.x >> 6;
    const int wm = w >> 1, wn = w & 1;
    const int g = lane >> 4, c = lane & 15;

    if (z < 2) {
#pragma unroll
        for (int ni = 0; ni < 4; ni++) {
            const int n = n0 + wn * 64 + ni * 16 + c;
            const float bb = bias[n];
            const int h = n >> 6, d = n & 63;
#pragma unroll
            for (int mi = 0; mi < 4; mi++) {
#pragma unroll
                for (int r = 0; r < 4; r++) {
                    const int m = m0 + wm * 64 + mi * 16 + g * 4 + r;
                    const int b = m >> 11, s = m & 2047;
                    outz[(((size_t)((b << 4) | h)) * 2048 + s) * 64 + d] =
                        (bf16)((acc[mi][ni][r] + bb) * oscale);
                }
            }
        }
    } else {
        // V transposed: [bh][d][s]; 4 regs = 4 consecutive s -> b64 store
#pragma unroll
        for (int ni = 0; ni < 4; ni++) {
            const int n = n0 + wn * 64 + ni * 16 + c;
            const float bb = bias[n];
            const int h = n >> 6, d = n & 63;
#pragma unroll
            for (int mi = 0; mi < 4; mi++) {
                const int m = m0 + wm * 64 + mi * 16 + g * 4;  // 4 consecutive s
                const int b = m >> 11, s = m & 2047;
                s4v pk;
#pragma unroll
                for (int r = 0; r < 4; r++)
                    pk[r] = __builtin_bit_cast(short, (bf16)(acc[mi][ni][r] + bb));
                *(s4v*)(outz + (((size_t)((b << 4) | h)) * 64 + d) * 2048 + s) = pk;
            }
        }
    }
}

// ---------------------------------------------------------------------------
// Stage 2: barrier-free flash attention. grid (16, 64), block 256 (4 waves).
// Each wave owns 32 queries; K-blocks of 128 keys; online softmax in base-2.
// S^T = K*Q^T  (C-layout: q = lane&15, key = (lane>>4)*4+reg)
// O^T = V^T*P  (C-layout: q = lane&15, d   = (lane>>4)*4+reg)
// ---------------------------------------------------------------------------
__global__ __launch_bounds__(256) void attn_kernel(
    const bf16* __restrict__ qkv, bf16* __restrict__ attn_out)
{
    __shared__ __align__(16) short Pq[4 * 32 * PQ_STRIDE];  // per-wave P: [32 q][128 key]

    const int bh = blockIdx.y;            // b = bh>>4, h = bh&15
    const int q0 = blockIdx.x * 128;
    const bf16* Q  = qkv + (size_t)bh * 131072u;                 // [s][64], pre-scaled
    const bf16* Kp = qkv + 8388608u + (size_t)bh * 131072u;      // [s][64]
    const bf16* Vt = qkv + 16777216u + (size_t)bh * 131072u;     // [64][2048]

    const int tid  = threadIdx.x;
    const int lane = tid & 63;
    const int w    = tid >> 6;
    const int g    = lane >> 4, c = lane & 15;
    short* Pw = Pq + w * 32 * PQ_STRIDE;

    // Q fragments (B-operand: n = lane&15 = q, k-contiguous), resident in regs
    short8 qf[2][2];
#pragma unroll
    for (int mi = 0; mi < 2; mi++)
#pragma unroll
        for (int ks = 0; ks < 2; ks++)
            qf[mi][ks] = *(const short8*)(Q + (size_t)(q0 + w * 32 + mi * 16 + c) * 64
                                            + ks * 32 + g * 8);

    floatx4 o[2][4];
#pragma unroll
    for (int mi = 0; mi < 2; mi++)
#pragma unroll
        for (int di = 0; di < 4; di++)
            o[mi][di] = (floatx4){0.f, 0.f, 0.f, 0.f};
    float m_run[2] = {-1e30f, -1e30f};
    float l_run[2] = {0.f, 0.f};

    for (int kb = 0; kb < 16; kb++) {
        const int k0 = kb * 128;

#pragma unroll
        for (int mi = 0; mi < 2; mi++) {
            // S^T = K * Q^T for this mi's 16 queries x 128 keys
            floatx4 sT[8];
#pragma unroll
            for (int ni = 0; ni < 8; ni++) sT[ni] = (floatx4){0.f, 0.f, 0.f, 0.f};
#pragma unroll
            for (int ks = 0; ks < 2; ks++) {
                short8 kf[8];
#pragma unroll
                for (int ni = 0; ni < 8; ni++)
                    kf[ni] = *(const short8*)(Kp + (size_t)(k0 + ni * 16 + c) * 64
                                                 + ks * 32 + g * 8);
#pragma unroll
                for (int ni = 0; ni < 8; ni++)
                    sT[ni] = MFMA16(kf[ni], qf[mi][ks], sT[ni]);
            }

            // per-lane online softmax stats (this lane's query = mi*16+c)
            float mx = -1e30f;
#pragma unroll
            for (int ni = 0; ni < 8; ni++)
#pragma unroll
                for (int r = 0; r < 4; r++) mx = fmaxf(mx, sT[ni][r]);
            mx = fmaxf(mx, __shfl_xor(mx, 16));
            mx = fmaxf(mx, __shfl_xor(mx, 32));
            const float mnew = fmaxf(m_run[mi], mx);
            const float alpha = exp2f(m_run[mi] - mnew);
            m_run[mi] = mnew;

            float sum = 0.f;
            short* prow = Pw + (mi * 16 + c) * PQ_STRIDE + g * 4;
#pragma unroll
            for (int ni = 0; ni < 8; ni++) {
                s4v pk;
#pragma unroll
                for (int r = 0; r < 4; r++) {
                    const float p = exp2f(sT[ni][r] - mnew);
                    sum += p;
                    pk[r] = __builtin_bit_cast(short, (bf16)p);
                }
                *(s4v*)(prow + ni * 16) = pk;  // 4 consecutive keys, one b64
            }
            sum += __shfl_xor(sum, 16);
            sum += __shfl_xor(sum, 32);
            l_run[mi] = l_run[mi] * alpha + sum;

#pragma unroll
            for (int di = 0; di < 4; di++)
#pragma unroll
                for (int r = 0; r < 4; r++) o[mi][di][r] *= alpha;
        }

        // O^T += V^T * P   (A = V^T from global, B = P from per-wave LDS)
#pragma unroll
        for (int ks2 = 0; ks2 < 4; ks2++) {
            short8 pf[2], vf[4];
#pragma unroll
            for (int mi = 0; mi < 2; mi++)
                pf[mi] = *(const short8*)(Pw + (mi * 16 + c) * PQ_STRIDE + ks2 * 32 + g * 8);
#pragma unroll
            for (int di = 0; di < 4; di++)
                vf[di] = *(const short8*)(Vt + (size_t)(di * 16 + c) * 2048
                                             + k0 + ks2 * 32 + g * 8);
#pragma unroll
            for (int mi = 0; mi < 2; mi++)
#pragma unroll
                for (int di = 0; di < 4; di++)
                    o[mi][di] = MFMA16(vf[di], pf[mi], o[mi][di]);
        }
        // no barrier: Pq region is per-wave private
    }

    // epilogue: O /= l; lane holds q = mi*16+c, d = di*16+g*4+r (4 consecutive d)
    const int b = bh >> 4, h = bh & 15;
#pragma unroll
    for (int mi = 0; mi < 2; mi++) {
        const float inv = 1.0f / l_run[mi];
        const int srow = q0 + w * 32 + mi * 16 + c;
#pragma unroll
        for (int di = 0; di < 4; di++) {
            s4v pk;
#pragma unroll
            for (int r = 0; r < 4; r++)
                pk[r] = __builtin_bit_cast(short, (bf16)(o[mi][di][r] * inv));
            *(s4v*)(attn_out + ((size_t)(b * 2048 + srow)) * 1024
                             + h * 64 + di * 16 + g * 4) = pk;
        }
    }
}

// ---------------------------------------------------------------------------
// Stage 3: out = attn @ Wo^T + bo -> fp32. grid (8, 64).
// ---------------------------------------------------------------------------
__global__ __launch_bounds__(256) void out_gemm(
    const bf16* __restrict__ A, const float* __restrict__ Wo,
    const float* __restrict__ bo, float* __restrict__ C)
{
    __shared__ __align__(16) short As[128 * LDS_STRIDE];
    __shared__ __align__(16) short Bs[128 * LDS_STRIDE];

    const int m0 = blockIdx.y * 128;
    const int n0 = blockIdx.x * 128;

    floatx4 acc[4][4];
    gemm128_core(A, Wo, 1024, m0, n0, As, Bs, acc);

    const int lane = threadIdx.x & 63;
    const int w = threadIdx.x >> 6;
    const int wm = w >> 1, wn = w & 1;
    const int g = lane >> 4, c = lane & 15;

#pragma unroll
    for (int ni = 0; ni < 4; ni++) {
        const int n = n0 + wn * 64 + ni * 16 + c;
        const float bb = bo[n];
#pragma unroll
        for (int mi = 0; mi < 4; mi++) {
#pragma unroll
            for (int r = 0; r < 4; r++) {
                const int m = m0 + wm * 64 + mi * 16 + g * 4 + r;
                C[(size_t)m * 1024 + n] = acc[mi][ni][r] + bb;
            }
        }
    }
}

// ---------------------------------------------------------------------------
extern "C" void kernel_launch(void* const* d_in, const int* in_sizes, int n_in,
                              void* d_out, int out_size, void* d_ws, size_t ws_size,
                              hipStream_t stream)
{
    const float* x  = (const float*)d_in[0];
    const float* Wq = (const float*)d_in[1];
    const float* bq = (const float*)d_in[2];
    const float* Wk = (const float*)d_in[3];
    const float* bk = (const float*)d_in[4];
    const float* Wv = (const float*)d_in[5];
    const float* bv = (const float*)d_in[6];
    const float* Wo = (const float*)d_in[7];
    const float* bo = (const float*)d_in[8];
    float* out = (float*)d_out;

    bf16* qkv  = (bf16*)d_ws;                       // 3 x 8192x1024 bf16 = 48 MB
    bf16* attn = qkv + 3u * 8192u * 1024u;          // 8192x1024 bf16 = 16 MB

    qkv_gemm<<<dim3(8, 64, 3), dim3(256), 0, stream>>>(x, Wq, Wk, Wv, bq, bk, bv, qkv);
    attn_kernel<<<dim3(16, 64), dim3(256), 0, stream>>>(qkv, attn);
    out_gemm<<<dim3(8, 64), dim3(256), 0, stream>>>(attn, Wo, bo, out);
}

// Round 4
// 534.015 us; speedup vs baseline: 1.2198x; 1.2198x over previous
//
#include <hip/hip_runtime.h>
#include <math.h>

// MultiHeadSelfAttention: B=4, S=2048, E=1024, H=16, Dh=64. fp32 in/out,
// bf16 MFMA internally, fp32 accumulate.
//
// Stage 1: qkv_gemm -> ws (bf16): q (pre-scaled by log2e/32) [bh][s][d],
//                                 k [bh][s][d], v TRANSPOSED [bh][d][s]
// Stage 2: attn     -> flash attention, S^T = K Q^T per-lane softmax,
//                      V^T tile LDS-staged per block, P per-wave in LDS.
// Stage 3: out_gemm -> @ Wo^T + bo -> d_out (fp32)

typedef __bf16 bf16;
typedef __attribute__((ext_vector_type(8))) short short8;
typedef __attribute__((ext_vector_type(4))) short s4v;
typedef __attribute__((ext_vector_type(4))) float floatx4;

#define MFMA16(a, b, c) __builtin_amdgcn_mfma_f32_16x16x32_bf16((a), (b), (c), 0, 0, 0)

#define LDS_STRIDE 56   // GEMM tiles: 32 -> 56 shorts (112 B)
#define VT_STRIDE 136   // V^T tile rows: 128 -> 136 shorts (272 B): 68 dw = 4 mod 32
#define PQ_STRIDE 136   // P rows: 128 -> 136 shorts

// Q pre-scale: (1/sqrt(1024)) * log2(e) -> softmax computed in base-2 domain
#define QSCALE 0.04508422002778f

__device__ __forceinline__ short8 frag8(const bf16* __restrict__ p) {
    return *(const short8*)p;
}
__device__ __forceinline__ short8 frag8(const float* __restrict__ p) {
    const floatx4 a = *(const floatx4*)p;
    const floatx4 b = *(const floatx4*)(p + 4);
    short8 r;
#pragma unroll
    for (int j = 0; j < 4; j++) {
        r[j]     = __builtin_bit_cast(short, (bf16)a[j]);
        r[4 + j] = __builtin_bit_cast(short, (bf16)b[j]);
    }
    return r;
}

// ---------------------------------------------------------------------------
// 128x128-tile GEMM core: C[m][n] = sum_k A[m][k] * B[n][k]
// ---------------------------------------------------------------------------
template <typename TA, typename TB>
__device__ __forceinline__ void gemm128_core(
    const TA* __restrict__ A, const TB* __restrict__ B, int K,
    int m0, int n0, short* As, short* Bs, floatx4 acc[4][4])
{
    const int tid  = threadIdx.x;
    const int lane = tid & 63;
    const int w    = tid >> 6;
    const int wm   = w >> 1, wn = w & 1;
    const int g    = lane >> 4, c = lane & 15;
    const int lrow = tid >> 2;
    const int lc8  = (tid & 3) * 8;

#pragma unroll
    for (int mi = 0; mi < 4; mi++)
#pragma unroll
        for (int ni = 0; ni < 4; ni++)
            acc[mi][ni] = (floatx4){0.f, 0.f, 0.f, 0.f};

    for (int k0 = 0; k0 < K; k0 += 32) {
        *(short8*)(As + lrow * LDS_STRIDE + lc8) =
            frag8(A + (size_t)(m0 + lrow) * K + k0 + lc8);
        *(short8*)(As + (lrow + 64) * LDS_STRIDE + lc8) =
            frag8(A + (size_t)(m0 + lrow + 64) * K + k0 + lc8);
        *(short8*)(Bs + lrow * LDS_STRIDE + lc8) =
            frag8(B + (size_t)(n0 + lrow) * K + k0 + lc8);
        *(short8*)(Bs + (lrow + 64) * LDS_STRIDE + lc8) =
            frag8(B + (size_t)(n0 + lrow + 64) * K + k0 + lc8);
        __syncthreads();

        short8 af[4], bfr[4];
#pragma unroll
        for (int mi = 0; mi < 4; mi++)
            af[mi] = *(const short8*)(As + (wm * 64 + mi * 16 + c) * LDS_STRIDE + g * 8);
#pragma unroll
        for (int ni = 0; ni < 4; ni++)
            bfr[ni] = *(const short8*)(Bs + (wn * 64 + ni * 16 + c) * LDS_STRIDE + g * 8);
#pragma unroll
        for (int mi = 0; mi < 4; mi++)
#pragma unroll
            for (int ni = 0; ni < 4; ni++)
                acc[mi][ni] = MFMA16(af[mi], bfr[ni], acc[mi][ni]);
        __syncthreads();
    }
}

// ---------------------------------------------------------------------------
// Stage 1: q/k/v projections. q scaled by QSCALE, [bh][s][64].
//          k plain [bh][s][64]. v stored TRANSPOSED [bh][64][2048].
// grid (8, 64, 3), block 256
// ---------------------------------------------------------------------------
__global__ __launch_bounds__(256) void qkv_gemm(
    const float* __restrict__ X,
    const float* __restrict__ Wq, const float* __restrict__ Wk, const float* __restrict__ Wv,
    const float* __restrict__ bq, const float* __restrict__ bk, const float* __restrict__ bv,
    bf16* __restrict__ qkv)
{
    __shared__ __align__(16) short As[128 * LDS_STRIDE];
    __shared__ __align__(16) short Bs[128 * LDS_STRIDE];

    const int z = blockIdx.z;
    const float* W    = (z == 0) ? Wq : (z == 1) ? Wk : Wv;
    const float* bias = (z == 0) ? bq : (z == 1) ? bk : bv;
    bf16* outz = qkv + (size_t)z * (8192u * 1024u);
    const float oscale = (z == 0) ? QSCALE : 1.0f;

    const int m0 = blockIdx.y * 128;
    const int n0 = blockIdx.x * 128;

    floatx4 acc[4][4];
    gemm128_core(X, W, 1024, m0, n0, As, Bs, acc);

    const int lane = threadIdx.x & 63;
    const int w = threadIdx.x >> 6;
    const int wm = w >> 1, wn = w & 1;
    const int g = lane >> 4, c = lane & 15;

    if (z < 2) {
#pragma unroll
        for (int ni = 0; ni < 4; ni++) {
            const int n = n0 + wn * 64 + ni * 16 + c;
            const float bb = bias[n];
            const int h = n >> 6, d = n & 63;
#pragma unroll
            for (int mi = 0; mi < 4; mi++) {
#pragma unroll
                for (int r = 0; r < 4; r++) {
                    const int m = m0 + wm * 64 + mi * 16 + g * 4 + r;
                    const int b = m >> 11, s = m & 2047;
                    outz[(((size_t)((b << 4) | h)) * 2048 + s) * 64 + d] =
                        (bf16)((acc[mi][ni][r] + bb) * oscale);
                }
            }
        }
    } else {
        // V transposed: [bh][d][s]; 4 regs = 4 consecutive s -> b64 store
#pragma unroll
        for (int ni = 0; ni < 4; ni++) {
            const int n = n0 + wn * 64 + ni * 16 + c;
            const float bb = bias[n];
            const int h = n >> 6, d = n & 63;
#pragma unroll
            for (int mi = 0; mi < 4; mi++) {
                const int m = m0 + wm * 64 + mi * 16 + g * 4;  // 4 consecutive s
                const int b = m >> 11, s = m & 2047;
                s4v pk;
#pragma unroll
                for (int r = 0; r < 4; r++)
                    pk[r] = __builtin_bit_cast(short, (bf16)(acc[mi][ni][r] + bb));
                *(s4v*)(outz + (((size_t)((b << 4) | h)) * 64 + d) * 2048 + s) = pk;
            }
        }
    }
}

// ---------------------------------------------------------------------------
// Stage 2: flash attention. grid (16, 64), block 256 (4 waves).
// Wave owns 32 queries; K-blocks of 128 keys; online softmax base-2.
// S^T = K*Q^T  (C-layout: q = lane&15, key = (lane>>4)*4+reg) -> per-lane stats
// V^T tile staged in LDS per block (shared by 4 waves); P per-wave in LDS.
// O^T = V^T*P  (C-layout: q = lane&15, d = (lane>>4)*4+reg)
// ---------------------------------------------------------------------------
__global__ __launch_bounds__(256) void attn_kernel(
    const bf16* __restrict__ qkv, bf16* __restrict__ attn_out)
{
    __shared__ __align__(16) short Vts[64 * VT_STRIDE];       // 17,408 B
    __shared__ __align__(16) short Pq[4 * 32 * PQ_STRIDE];    // 34,816 B

    const int bh = blockIdx.y;            // b = bh>>4, h = bh&15
    const int q0 = blockIdx.x * 128;
    const bf16* Q   = qkv + (size_t)bh * 131072u;                 // [s][64], pre-scaled
    const bf16* Kp  = qkv + 8388608u + (size_t)bh * 131072u;      // [s][64]
    const bf16* Vtg = qkv + 16777216u + (size_t)bh * 131072u;     // [64][2048]

    const int tid  = threadIdx.x;
    const int lane = tid & 63;
    const int w    = tid >> 6;
    const int g    = lane >> 4, c = lane & 15;
    short* Pw = Pq + w * 32 * PQ_STRIDE;

    // V^T staging map: per i, 16-lane cluster reads one 256B row segment
    const int vrow = tid >> 4;           // 0..15 (+ i*16)
    const int vcol = (tid & 15) * 8;     // 0..120 shorts

    // Q fragments (B-operand: n = lane&15 = q, k-contiguous), resident in regs
    short8 qf[2][2];
#pragma unroll
    for (int mi = 0; mi < 2; mi++)
#pragma unroll
        for (int ks = 0; ks < 2; ks++)
            qf[mi][ks] = *(const short8*)(Q + (size_t)(q0 + w * 32 + mi * 16 + c) * 64
                                            + ks * 32 + g * 8);

    floatx4 o[2][4];
#pragma unroll
    for (int mi = 0; mi < 2; mi++)
#pragma unroll
        for (int di = 0; di < 4; di++)
            o[mi][di] = (floatx4){0.f, 0.f, 0.f, 0.f};
    float m_run[2] = {-1e30f, -1e30f};
    float l_run[2] = {0.f, 0.f};

    for (int kb = 0; kb < 16; kb++) {
        const int k0 = kb * 128;

        __syncthreads();  // prev iteration's PV reads of Vts complete

        // stage V^T tile (straight copy, b128 in/out)
        short8 vst[4];
#pragma unroll
        for (int i = 0; i < 4; i++)
            vst[i] = *(const short8*)(Vtg + (size_t)(vrow + i * 16) * 2048 + k0 + vcol);
#pragma unroll
        for (int i = 0; i < 4; i++)
            *(short8*)(Vts + (vrow + i * 16) * VT_STRIDE + vcol) = vst[i];

        // S^T = K * Q^T : 32 queries x 128 keys (kf shared across both mi)
        floatx4 sT[2][8];
#pragma unroll
        for (int mi = 0; mi < 2; mi++)
#pragma unroll
            for (int ni = 0; ni < 8; ni++) sT[mi][ni] = (floatx4){0.f, 0.f, 0.f, 0.f};
#pragma unroll
        for (int ks = 0; ks < 2; ks++) {
            short8 kf[8];
#pragma unroll
            for (int ni = 0; ni < 8; ni++)
                kf[ni] = *(const short8*)(Kp + (size_t)(k0 + ni * 16 + c) * 64
                                             + ks * 32 + g * 8);
#pragma unroll
            for (int mi = 0; mi < 2; mi++)
#pragma unroll
                for (int ni = 0; ni < 8; ni++)
                    sT[mi][ni] = MFMA16(kf[ni], qf[mi][ks], sT[mi][ni]);
        }

        // per-lane online softmax (lane's query = mi*16 + c), base-2 domain
#pragma unroll
        for (int mi = 0; mi < 2; mi++) {
            float mx = -1e30f;
#pragma unroll
            for (int ni = 0; ni < 8; ni++)
#pragma unroll
                for (int r = 0; r < 4; r++) mx = fmaxf(mx, sT[mi][ni][r]);
            mx = fmaxf(mx, __shfl_xor(mx, 16));
            mx = fmaxf(mx, __shfl_xor(mx, 32));
            const float mnew = fmaxf(m_run[mi], mx);
            const float alpha = exp2f(m_run[mi] - mnew);
            m_run[mi] = mnew;

            float sum = 0.f;
            short* prow = Pw + (mi * 16 + c) * PQ_STRIDE + g * 4;
#pragma unroll
            for (int ni = 0; ni < 8; ni++) {
                s4v pk;
#pragma unroll
                for (int r = 0; r < 4; r++) {
                    const float p = exp2f(sT[mi][ni][r] - mnew);
                    sum += p;
                    pk[r] = __builtin_bit_cast(short, (bf16)p);
                }
                *(s4v*)(prow + ni * 16) = pk;  // 4 consecutive keys, one b64
            }
            sum += __shfl_xor(sum, 16);
            sum += __shfl_xor(sum, 32);
            l_run[mi] = l_run[mi] * alpha + sum;

#pragma unroll
            for (int di = 0; di < 4; di++)
#pragma unroll
                for (int r = 0; r < 4; r++) o[mi][di][r] *= alpha;
        }

        __syncthreads();  // Vts staged & visible (P is per-wave private)

        // O^T += V^T * P   (A = V^T frag from LDS, B = P frag from per-wave LDS)
#pragma unroll
        for (int ks2 = 0; ks2 < 4; ks2++) {
            short8 pf[2], vf[4];
#pragma unroll
            for (int mi = 0; mi < 2; mi++)
                pf[mi] = *(const short8*)(Pw + (mi * 16 + c) * PQ_STRIDE + ks2 * 32 + g * 8);
#pragma unroll
            for (int di = 0; di < 4; di++)
                vf[di] = *(const short8*)(Vts + (di * 16 + c) * VT_STRIDE + ks2 * 32 + g * 8);
#pragma unroll
            for (int mi = 0; mi < 2; mi++)
#pragma unroll
                for (int di = 0; di < 4; di++)
                    o[mi][di] = MFMA16(vf[di], pf[mi], o[mi][di]);
        }
    }

    // epilogue: O /= l; lane holds q = mi*16+c, d = di*16+g*4+r (4 consecutive d)
    const int b = bh >> 4, h = bh & 15;
#pragma unroll
    for (int mi = 0; mi < 2; mi++) {
        const float inv = 1.0f / l_run[mi];
        const int srow = q0 + w * 32 + mi * 16 + c;
#pragma unroll
        for (int di = 0; di < 4; di++) {
            s4v pk;
#pragma unroll
            for (int r = 0; r < 4; r++)
                pk[r] = __builtin_bit_cast(short, (bf16)(o[mi][di][r] * inv));
            *(s4v*)(attn_out + ((size_t)(b * 2048 + srow)) * 1024
                             + h * 64 + di * 16 + g * 4) = pk;
        }
    }
}

// ---------------------------------------------------------------------------
// Stage 3: out = attn @ Wo^T + bo -> fp32. grid (8, 64).
// ---------------------------------------------------------------------------
__global__ __launch_bounds__(256) void out_gemm(
    const bf16* __restrict__ A, const float* __restrict__ Wo,
    const float* __restrict__ bo, float* __restrict__ C)
{
    __shared__ __align__(16) short As[128 * LDS_STRIDE];
    __shared__ __align__(16) short Bs[128 * LDS_STRIDE];

    const int m0 = blockIdx.y * 128;
    const int n0 = blockIdx.x * 128;

    floatx4 acc[4][4];
    gemm128_core(A, Wo, 1024, m0, n0, As, Bs, acc);

    const int lane = threadIdx.x & 63;
    const int w = threadIdx.x >> 6;
    const int wm = w >> 1, wn = w & 1;
    const int g = lane >> 4, c = lane & 15;

#pragma unroll
    for (int ni = 0; ni < 4; ni++) {
        const int n = n0 + wn * 64 + ni * 16 + c;
        const float bb = bo[n];
#pragma unroll
        for (int mi = 0; mi < 4; mi++) {
#pragma unroll
            for (int r = 0; r < 4; r++) {
                const int m = m0 + wm * 64 + mi * 16 + g * 4 + r;
                C[(size_t)m * 1024 + n] = acc[mi][ni][r] + bb;
            }
        }
    }
}

// ---------------------------------------------------------------------------
extern "C" void kernel_launch(void* const* d_in, const int* in_sizes, int n_in,
                              void* d_out, int out_size, void* d_ws, size_t ws_size,
                              hipStream_t stream)
{
    const float* x  = (const float*)d_in[0];
    const float* Wq = (const float*)d_in[1];
    const float* bq = (const float*)d_in[2];
    const float* Wk = (const float*)d_in[3];
    const float* bk = (const float*)d_in[4];
    const float* Wv = (const float*)d_in[5];
    const float* bv = (const float*)d_in[6];
    const float* Wo = (const float*)d_in[7];
    const float* bo = (const float*)d_in[8];
    float* out = (float*)d_out;

    bf16* qkv  = (bf16*)d_ws;                       // 3 x 8192x1024 bf16 = 48 MB
    bf16* attn = qkv + 3u * 8192u * 1024u;          // 8192x1024 bf16 = 16 MB

    qkv_gemm<<<dim3(8, 64, 3), dim3(256), 0, stream>>>(x, Wq, Wk, Wv, bq, bk, bv, qkv);
    attn_kernel<<<dim3(16, 64), dim3(256), 0, stream>>>(qkv, attn);
    out_gemm<<<dim3(8, 64), dim3(256), 0, stream>>>(attn, Wo, bo, out);
}